// Round 9
// baseline (797.119 us; speedup 1.0000x reference)
//
#include <hip/hip_runtime.h>

#define NB  64
#define IC  2048
#define ID  16
#define DD  256
#define DDSQ 65536
#define PB  (DDSQ * NB)       // 4,194,304 floats = one full-batch matrix buffer
#define NSQ 11                // matrix squarings
#define NPI 7                 // finish matvecs: exponent 2^11 * 8 = 16384

#define FMA4(c, s, v) { (c).x = fmaf((s), (v).x, (c).x); (c).y = fmaf((s), (v).y, (c).y); \
                        (c).z = fmaf((s), (v).z, (c).z); (c).w = fmaf((s), (v).w, (c).w); }
#define F4Z make_float4(0.f, 0.f, 0.f, 0.f)
#define SCL4(c, s) { (c).x *= (s); (c).y *= (s); (c).z *= (s); (c).w *= (s); }
#define ADDF4(a, b) { (a).x += (b).x; (a).y += (b).y; (a).z += (b).z; (a).w += (b).w; }
// trace contribution: named float4 ci at micro-row i, cols off+4*te..+3
#define TRC(ci, i, off) { if (8*td+(i) == (off)+4*te+0) ts += (ci).x; \
                          if (8*td+(i) == (off)+4*te+1) ts += (ci).y; \
                          if (8*td+(i) == (off)+4*te+2) ts += (ci).z; \
                          if (8*td+(i) == (off)+4*te+3) ts += (ci).w; }
#define STROW2(dst, cl, ch, i) { \
    *(float4*)&(dst)[(size_t)(d0 + 8*td + (i)) * DD + e0 + 4*te]      = (cl); \
    *(float4*)&(dst)[(size_t)(d0 + 8*td + (i)) * DD + e0 + 64 + 4*te] = (ch); }

// ---------------- stage 1: u[b,c,:] = x[b,c,:] @ W_c (16 batches/block) -----
__global__ __launch_bounds__(256, 4) void u_kernel(const float* __restrict__ caps,
                                                   const float* __restrict__ W,
                                                   float* __restrict__ U) {
    const int c  = blockIdx.x;
    const int b0 = blockIdx.y * 16;
    const int t  = threadIdx.x;
    __shared__ float xsT[ID][16];        // [dim][batch]
    if (t < 64) {
        const int b = t >> 2, q = (t & 3) * 4;
        const float4 x4 = *(const float4*)&caps[((size_t)(b0 + b) * IC + c) * ID + q];
        xsT[q + 0][b] = x4.x; xsT[q + 1][b] = x4.y;
        xsT[q + 2][b] = x4.z; xsT[q + 3][b] = x4.w;
    }
    __syncthreads();
    float a0 = 0.f, a1 = 0.f, a2 = 0.f, a3 = 0.f, a4 = 0.f, a5 = 0.f, a6 = 0.f, a7 = 0.f;
    float a8 = 0.f, a9 = 0.f, a10 = 0.f, a11 = 0.f, a12 = 0.f, a13 = 0.f, a14 = 0.f, a15 = 0.f;
#pragma unroll
    for (int i = 0; i < ID; ++i) {
        const float wi = W[((size_t)c * ID + i) * DD + t];    // coalesced over t
        const float4 x0 = *(const float4*)&xsT[i][0];
        const float4 x1 = *(const float4*)&xsT[i][4];
        const float4 x2 = *(const float4*)&xsT[i][8];
        const float4 x3 = *(const float4*)&xsT[i][12];
        a0  = fmaf(x0.x, wi, a0 );  a1  = fmaf(x0.y, wi, a1 );
        a2  = fmaf(x0.z, wi, a2 );  a3  = fmaf(x0.w, wi, a3 );
        a4  = fmaf(x1.x, wi, a4 );  a5  = fmaf(x1.y, wi, a5 );
        a6  = fmaf(x1.z, wi, a6 );  a7  = fmaf(x1.w, wi, a7 );
        a8  = fmaf(x2.x, wi, a8 );  a9  = fmaf(x2.y, wi, a9 );
        a10 = fmaf(x2.z, wi, a10);  a11 = fmaf(x2.w, wi, a11);
        a12 = fmaf(x3.x, wi, a12);  a13 = fmaf(x3.y, wi, a13);
        a14 = fmaf(x3.z, wi, a14);  a15 = fmaf(x3.w, wi, a15);
    }
    U[((size_t)(b0 +  0) * IC + c) * DD + t] = a0;
    U[((size_t)(b0 +  1) * IC + c) * DD + t] = a1;
    U[((size_t)(b0 +  2) * IC + c) * DD + t] = a2;
    U[((size_t)(b0 +  3) * IC + c) * DD + t] = a3;
    U[((size_t)(b0 +  4) * IC + c) * DD + t] = a4;
    U[((size_t)(b0 +  5) * IC + c) * DD + t] = a5;
    U[((size_t)(b0 +  6) * IC + c) * DD + t] = a6;
    U[((size_t)(b0 +  7) * IC + c) * DD + t] = a7;
    U[((size_t)(b0 +  8) * IC + c) * DD + t] = a8;
    U[((size_t)(b0 +  9) * IC + c) * DD + t] = a9;
    U[((size_t)(b0 + 10) * IC + c) * DD + t] = a10;
    U[((size_t)(b0 + 11) * IC + c) * DD + t] = a11;
    U[((size_t)(b0 + 12) * IC + c) * DD + t] = a12;
    U[((size_t)(b0 + 13) * IC + c) * DD + t] = a13;
    U[((size_t)(b0 + 14) * IC + c) * DD + t] = a14;
    U[((size_t)(b0 + 15) * IC + c) * DD + t] = a15;
}

// ---- stage 2: partial C, 128x128 tile, 8x8 micro (16 named float4) ---------
// id: low6 = batch; tk = id>>6 (0..7): tile = tk>>1 (2x2 grid), kch = tk&1
__global__ __launch_bounds__(256, 2)
void c_kernel(const float* __restrict__ U,
              float* __restrict__ P0, float* __restrict__ P1,
              float* __restrict__ Sc) {
    const int id   = blockIdx.x;
    const int bb   = id & 63;
    const int tk   = id >> 6;
    const int tile = tk >> 1, kch = tk & 1;
    const int tr = tile >> 1, tc = tile & 1;
    const int d0 = tr * 128, e0 = tc * 128;
    const int t  = threadIdx.x;
    const int td = t >> 4, te = t & 15;
    const int sr = t >> 5, sc4 = (t & 31) * 4;
    __shared__ float Ad[32][128];
    __shared__ float Ae[32][128];
    __shared__ float red[256];
    float4 cL0 = F4Z, cL1 = F4Z, cL2 = F4Z, cL3 = F4Z;
    float4 cL4 = F4Z, cL5 = F4Z, cL6 = F4Z, cL7 = F4Z;
    float4 cH0 = F4Z, cH1 = F4Z, cH2 = F4Z, cH3 = F4Z;
    float4 cH4 = F4Z, cH5 = F4Z, cH6 = F4Z, cH7 = F4Z;
    const float* Ub = U + (size_t)bb * IC * DD;
    const int k0 = kch * (IC / 2);
    for (int kb = k0; kb < k0 + IC / 2; kb += 32) {
        const float4 ra0 = *(const float4*)&Ub[(size_t)(kb +  0 + sr) * DD + d0 + sc4];
        const float4 ra1 = *(const float4*)&Ub[(size_t)(kb +  8 + sr) * DD + d0 + sc4];
        const float4 ra2 = *(const float4*)&Ub[(size_t)(kb + 16 + sr) * DD + d0 + sc4];
        const float4 ra3 = *(const float4*)&Ub[(size_t)(kb + 24 + sr) * DD + d0 + sc4];
        const float4 rb0 = *(const float4*)&Ub[(size_t)(kb +  0 + sr) * DD + e0 + sc4];
        const float4 rb1 = *(const float4*)&Ub[(size_t)(kb +  8 + sr) * DD + e0 + sc4];
        const float4 rb2 = *(const float4*)&Ub[(size_t)(kb + 16 + sr) * DD + e0 + sc4];
        const float4 rb3 = *(const float4*)&Ub[(size_t)(kb + 24 + sr) * DD + e0 + sc4];
        __syncthreads();
        *(float4*)&Ad[ 0 + sr][sc4] = ra0;
        *(float4*)&Ad[ 8 + sr][sc4] = ra1;
        *(float4*)&Ad[16 + sr][sc4] = ra2;
        *(float4*)&Ad[24 + sr][sc4] = ra3;
        *(float4*)&Ae[ 0 + sr][sc4] = rb0;
        *(float4*)&Ae[ 8 + sr][sc4] = rb1;
        *(float4*)&Ae[16 + sr][sc4] = rb2;
        *(float4*)&Ae[24 + sr][sc4] = rb3;
        __syncthreads();
#pragma unroll 4
        for (int k = 0; k < 32; ++k) {
            const float4 aL = *(const float4*)&Ad[k][8 * td];
            const float4 aH = *(const float4*)&Ad[k][8 * td + 4];
            const float4 bL = *(const float4*)&Ae[k][4 * te];
            const float4 bH = *(const float4*)&Ae[k][64 + 4 * te];
            FMA4(cL0, aL.x, bL); FMA4(cH0, aL.x, bH);
            FMA4(cL1, aL.y, bL); FMA4(cH1, aL.y, bH);
            FMA4(cL2, aL.z, bL); FMA4(cH2, aL.z, bH);
            FMA4(cL3, aL.w, bL); FMA4(cH3, aL.w, bH);
            FMA4(cL4, aH.x, bL); FMA4(cH4, aH.x, bH);
            FMA4(cL5, aH.y, bL); FMA4(cH5, aH.y, bH);
            FMA4(cL6, aH.z, bL); FMA4(cH6, aH.z, bH);
            FMA4(cL7, aH.w, bL); FMA4(cH7, aH.w, bH);
        }
    }
    float* Pb = (kch ? P1 : P0) + (size_t)bb * DDSQ;
    STROW2(Pb, cL0, cH0, 0); STROW2(Pb, cL1, cH1, 1);
    STROW2(Pb, cL2, cH2, 2); STROW2(Pb, cL3, cH3, 3);
    STROW2(Pb, cL4, cH4, 4); STROW2(Pb, cL5, cH5, 5);
    STROW2(Pb, cL6, cH6, 6); STROW2(Pb, cL7, cH7, 7);
    if (tr == tc) {                      // diagonal tile: fused partial trace
        float ts = 0.f;
        TRC(cL0, 0, 0); TRC(cL1, 1, 0); TRC(cL2, 2, 0); TRC(cL3, 3, 0);
        TRC(cL4, 4, 0); TRC(cL5, 5, 0); TRC(cL6, 6, 0); TRC(cL7, 7, 0);
        TRC(cH0, 0, 64); TRC(cH1, 1, 64); TRC(cH2, 2, 64); TRC(cH3, 3, 64);
        TRC(cH4, 4, 64); TRC(cH5, 5, 64); TRC(cH6, 6, 64); TRC(cH7, 7, 64);
        red[t] = ts;
        __syncthreads();
        for (int s = 128; s > 0; s >>= 1) {
            if (t < s) red[t] += red[t + s];
            __syncthreads();
        }
        if (t == 0) atomicAdd(&Sc[bb], red[0]);
    }
}

// ---- E0/E1 = k-split of ((D0+D1)/s)^2, 128x128 tile, 8x8 micro -------------
__global__ __launch_bounds__(256, 2)
void sq_kernel(const float* __restrict__ D0, const float* __restrict__ D1,
               float* __restrict__ E0, float* __restrict__ E1,
               const float* __restrict__ s_in, float* __restrict__ s_out) {
    const int id   = blockIdx.x;          // 512 blocks
    const int bb   = id & 63;
    const int tk   = id >> 6;             // 0..7
    const int tile = tk >> 1, kch = tk & 1;
    const int tr = tile >> 1, tc = tile & 1;
    const int d0 = tr * 128, e0 = tc * 128;
    const int t  = threadIdx.x;
    const int td = t >> 4, te = t & 15;
    const int sr = t >> 5, sc4 = (t & 31) * 4;
    __shared__ float Ad[32][128];
    __shared__ float Ae[32][128];
    __shared__ float red[256];
    float4 cL0 = F4Z, cL1 = F4Z, cL2 = F4Z, cL3 = F4Z;
    float4 cL4 = F4Z, cL5 = F4Z, cL6 = F4Z, cL7 = F4Z;
    float4 cH0 = F4Z, cH1 = F4Z, cH2 = F4Z, cH3 = F4Z;
    float4 cH4 = F4Z, cH5 = F4Z, cH6 = F4Z, cH7 = F4Z;
    const size_t mb = (size_t)bb * DDSQ;
    const float s = s_in[bb];
    const float inv = 1.f / (s * s);
    const int k0 = kch * (DD / 2);
    for (int kb = k0; kb < k0 + DD / 2; kb += 32) {
        const size_t r0 = mb + (size_t)(kb +  0 + sr) * DD + d0 + sc4;
        const size_t r1 = mb + (size_t)(kb +  8 + sr) * DD + d0 + sc4;
        const size_t r2 = mb + (size_t)(kb + 16 + sr) * DD + d0 + sc4;
        const size_t r3 = mb + (size_t)(kb + 24 + sr) * DD + d0 + sc4;
        const size_t q0 = mb + (size_t)(kb +  0 + sr) * DD + e0 + sc4;
        const size_t q1 = mb + (size_t)(kb +  8 + sr) * DD + e0 + sc4;
        const size_t q2 = mb + (size_t)(kb + 16 + sr) * DD + e0 + sc4;
        const size_t q3 = mb + (size_t)(kb + 24 + sr) * DD + e0 + sc4;
        float4 ra0 = *(const float4*)&D0[r0]; { const float4 x = *(const float4*)&D1[r0]; ADDF4(ra0, x); }
        float4 ra1 = *(const float4*)&D0[r1]; { const float4 x = *(const float4*)&D1[r1]; ADDF4(ra1, x); }
        float4 ra2 = *(const float4*)&D0[r2]; { const float4 x = *(const float4*)&D1[r2]; ADDF4(ra2, x); }
        float4 ra3 = *(const float4*)&D0[r3]; { const float4 x = *(const float4*)&D1[r3]; ADDF4(ra3, x); }
        float4 rb0 = *(const float4*)&D0[q0]; { const float4 x = *(const float4*)&D1[q0]; ADDF4(rb0, x); }
        float4 rb1 = *(const float4*)&D0[q1]; { const float4 x = *(const float4*)&D1[q1]; ADDF4(rb1, x); }
        float4 rb2 = *(const float4*)&D0[q2]; { const float4 x = *(const float4*)&D1[q2]; ADDF4(rb2, x); }
        float4 rb3 = *(const float4*)&D0[q3]; { const float4 x = *(const float4*)&D1[q3]; ADDF4(rb3, x); }
        __syncthreads();
        *(float4*)&Ad[ 0 + sr][sc4] = ra0;
        *(float4*)&Ad[ 8 + sr][sc4] = ra1;
        *(float4*)&Ad[16 + sr][sc4] = ra2;
        *(float4*)&Ad[24 + sr][sc4] = ra3;
        *(float4*)&Ae[ 0 + sr][sc4] = rb0;
        *(float4*)&Ae[ 8 + sr][sc4] = rb1;
        *(float4*)&Ae[16 + sr][sc4] = rb2;
        *(float4*)&Ae[24 + sr][sc4] = rb3;
        __syncthreads();
#pragma unroll 4
        for (int k = 0; k < 32; ++k) {
            const float4 aL = *(const float4*)&Ad[k][8 * td];
            const float4 aH = *(const float4*)&Ad[k][8 * td + 4];
            const float4 bL = *(const float4*)&Ae[k][4 * te];
            const float4 bH = *(const float4*)&Ae[k][64 + 4 * te];
            FMA4(cL0, aL.x, bL); FMA4(cH0, aL.x, bH);
            FMA4(cL1, aL.y, bL); FMA4(cH1, aL.y, bH);
            FMA4(cL2, aL.z, bL); FMA4(cH2, aL.z, bH);
            FMA4(cL3, aL.w, bL); FMA4(cH3, aL.w, bH);
            FMA4(cL4, aH.x, bL); FMA4(cH4, aH.x, bH);
            FMA4(cL5, aH.y, bL); FMA4(cH5, aH.y, bH);
            FMA4(cL6, aH.z, bL); FMA4(cH6, aH.z, bH);
            FMA4(cL7, aH.w, bL); FMA4(cH7, aH.w, bH);
        }
    }
    SCL4(cL0, inv); SCL4(cL1, inv); SCL4(cL2, inv); SCL4(cL3, inv);
    SCL4(cL4, inv); SCL4(cL5, inv); SCL4(cL6, inv); SCL4(cL7, inv);
    SCL4(cH0, inv); SCL4(cH1, inv); SCL4(cH2, inv); SCL4(cH3, inv);
    SCL4(cH4, inv); SCL4(cH5, inv); SCL4(cH6, inv); SCL4(cH7, inv);
    float* Eb = (kch ? E1 : E0) + mb;
    STROW2(Eb, cL0, cH0, 0); STROW2(Eb, cL1, cH1, 1);
    STROW2(Eb, cL2, cH2, 2); STROW2(Eb, cL3, cH3, 3);
    STROW2(Eb, cL4, cH4, 4); STROW2(Eb, cL5, cH5, 5);
    STROW2(Eb, cL6, cH6, 6); STROW2(Eb, cL7, cH7, 7);
    if (tr == tc) {
        float ts = 0.f;
        TRC(cL0, 0, 0); TRC(cL1, 1, 0); TRC(cL2, 2, 0); TRC(cL3, 3, 0);
        TRC(cL4, 4, 0); TRC(cL5, 5, 0); TRC(cL6, 6, 0); TRC(cL7, 7, 0);
        TRC(cH0, 0, 64); TRC(cH1, 1, 64); TRC(cH2, 2, 64); TRC(cH3, 3, 64);
        TRC(cH4, 4, 64); TRC(cH5, 5, 64); TRC(cH6, 6, 64); TRC(cH7, 7, 64);
        red[t] = ts;
        __syncthreads();
        for (int s2 = 128; s2 > 0; s2 >>= 1) {
            if (t < s2) red[t] += red[t + s2];
            __syncthreads();
        }
        if (t == 0) atomicAdd(&s_out[bb], red[0]);
    }
}

// -- finish: D = D0+D1; column start + NPI matvecs (no renorm; lambda1 ~ 1) --
__global__ __launch_bounds__(256, 2) void finish_kernel(const float* __restrict__ D0,
                                                        const float* __restrict__ D1,
                                                        float* __restrict__ out) {
    const int b = blockIdx.x, t = threadIdx.x;
    const size_t mb = (size_t)b * DDSQ;
    __shared__ float vs[DD];
    __shared__ float red[DD];
    __shared__ int   ridx[DD];
    red[t] = D0[mb + (size_t)t * DD + t] + D1[mb + (size_t)t * DD + t];
    ridx[t] = t;
    __syncthreads();
    for (int s = 128; s > 0; s >>= 1) {
        if (t < s && red[t + s] > red[t]) { red[t] = red[t + s]; ridx[t] = ridx[t + s]; }
        __syncthreads();
    }
    const int jmax0 = ridx[0];
    __syncthreads();
    float v = D0[mb + (size_t)jmax0 * DD + t] + D1[mb + (size_t)jmax0 * DD + t];
    for (int it = 0; it < NPI; ++it) {
        vs[t] = v;
        __syncthreads();
        float a = 0.f;
        const float* r0 = D0 + mb + (size_t)t * DD;
        const float* r1 = D1 + mb + (size_t)t * DD;
#pragma unroll 8
        for (int j = 0; j < DD; j += 4) {
            const float4 d4 = *(const float4*)&r0[j];
            const float4 e4 = *(const float4*)&r1[j];
            a = fmaf(d4.x + e4.x, vs[j],     a);
            a = fmaf(d4.y + e4.y, vs[j + 1], a);
            a = fmaf(d4.z + e4.z, vs[j + 2], a);
            a = fmaf(d4.w + e4.w, vs[j + 3], a);
        }
        __syncthreads();
        v = a;
    }
    vs[t] = v;
    red[t] = v * v;
    __syncthreads();
    for (int s = 128; s > 0; s >>= 1) {
        if (t < s) red[t] += red[t + s];
        __syncthreads();
    }
    const float nrm = sqrtf(red[0]);
    __syncthreads();
    red[t] = fabsf(v);
    ridx[t] = t;
    __syncthreads();
    for (int s = 128; s > 0; s >>= 1) {
        if (t < s && red[t + s] > red[t]) { red[t] = red[t + s]; ridx[t] = ridx[t + s]; }
        __syncthreads();
    }
    const float sgn = (vs[ridx[0]] < 0.f) ? -1.f : 1.f;
    out[(size_t)b * DD + t] = sgn * v / nrm;
}

extern "C" void kernel_launch(void* const* d_in, const int* in_sizes, int n_in,
                              void* d_out, int out_size, void* d_ws, size_t ws_size,
                              hipStream_t stream) {
    const float* caps = (const float*)d_in[0];   // (64, 2048, 16)
    const float* W    = (const float*)d_in[1];   // (2048, 16, 256)
    float* out = (float*)d_out;                  // (64, 256)
    float* ws  = (float*)d_ws;

    // layout: U = 8*PB @0 | A0 @8PB | A1 @9PB | Sc @10PB  (~168 MB, as R7/R8)
    float* U  = ws;
    float* A0 = ws + (size_t)8 * PB;
    float* A1 = ws + (size_t)9 * PB;
    float* Sc = ws + (size_t)10 * PB;
    float* X0 = ws;                  // sq ping-pong pair X overlays dead U
    float* X1 = ws + PB;
    float* Y0 = A0;                  // pair Y reuses A (dead after first sq)
    float* Y1 = A1;

    hipMemsetAsync(Sc, 0, 2048 * sizeof(float), stream);

    u_kernel<<<dim3(IC, 4), 256, 0, stream>>>(caps, W, U);
    c_kernel<<<512, 256, 0, stream>>>(U, A0, A1, Sc);

    // all squarings fold the previous k-split pair and emit a new split pair
    float *p0 = A0, *p1 = A1, *q0 = X0, *q1 = X1;
    for (int it = 0; it < NSQ; ++it) {
        sq_kernel<<<512, 256, 0, stream>>>(p0, p1, q0, q1,
                                           Sc + it * 64, Sc + (it + 1) * 64);
        float* t0 = p0; float* t1 = p1;
        p0 = q0; p1 = q1; q0 = t0; q1 = t1;
    }

    finish_kernel<<<NB, 256, 0, stream>>>(p0, p1, out);
}